// Round 1
// baseline (1861.062 us; speedup 1.0000x reference)
//
#include <hip/hip_runtime.h>
#include <math.h>

#define N_STEPS 50
#define DT 0.02f

// Two-hidden-layer MLP, input x[4], hidden 64/64, NOUT outputs.
// Weights are wave-uniform -> all weight indices are loop-uniform so the
// compiler emits s_load (SGPR operand to v_fmac), costing no VALU slots.
// Layer1 is fused into the layer2 i-loop so no h1[64] register array with
// a dynamic index exists; acc[64] is only indexed by unrolled constants.
template <int NOUT>
__device__ inline void mlp2(const float* __restrict__ W1, const float* __restrict__ b1,
                            const float* __restrict__ W2, const float* __restrict__ b2,
                            const float* __restrict__ W3, const float* __restrict__ b3,
                            float x0, float x1, float x2, float x3,
                            float* __restrict__ outv)
{
    float acc[64];
#pragma unroll
    for (int j = 0; j < 64; ++j) acc[j] = b2[j];

    for (int i = 0; i < 64; ++i) {            // rolled: small code, uniform s_loads
        float h = b1[i];
        h = fmaf(x0, W1[i],        h);
        h = fmaf(x1, W1[64 + i],   h);
        h = fmaf(x2, W1[128 + i],  h);
        h = fmaf(x3, W1[192 + i],  h);
        h = fmaxf(h, 0.0f);
        const float* __restrict__ w2row = W2 + i * 64;
#pragma unroll
        for (int j = 0; j < 64; ++j) acc[j] = fmaf(h, w2row[j], acc[j]);
    }

#pragma unroll
    for (int c = 0; c < NOUT; ++c) outv[c] = b3[c];
#pragma unroll
    for (int j = 0; j < 64; ++j) {
        float hr = fmaxf(acc[j], 0.0f);
#pragma unroll
        for (int c = 0; c < NOUT; ++c) outv[c] = fmaf(hr, W3[j * NOUT + c], outv[c]);
    }
}

__global__ __launch_bounds__(256) void bsde_kernel(
    const float* __restrict__ y0v, const float* __restrict__ Y0v,
    const float* __restrict__ qW1, const float* __restrict__ qb1,
    const float* __restrict__ qW2, const float* __restrict__ qb2,
    const float* __restrict__ qW3, const float* __restrict__ qb3,
    const float* __restrict__ zW1, const float* __restrict__ zb1,
    const float* __restrict__ zW2, const float* __restrict__ zb2,
    const float* __restrict__ zW3, const float* __restrict__ zb3,
    const float* __restrict__ dW,
    float* __restrict__ out, int B)
{
    const int b = blockIdx.x * blockDim.x + threadIdx.x;
    const float sqrt_dt = sqrtf(DT);

    float y0 = y0v[0], y1 = y0v[1], y2 = y0v[2];
    float Y  = Y0v[0];

    for (int n = 0; n < N_STEPS; ++n) {
        const float t = (float)n * DT;

        float z[3];
        mlp2<3>(zW1, zb1, zW2, zb2, zW3, zb3, t, y0, y1, y2, z);
        float q[1];
        mlp2<1>(qW1, qb1, qW2, qb2, qW3, qb3, t, y0, y1, y2, q);
        const float qq = q[0];
        const float f  = 0.5f * qq * qq;

        const size_t idx = ((size_t)n * (size_t)B + (size_t)b) * 3;
        const float dw0 = dW[idx + 0] * sqrt_dt;
        const float dw1 = dW[idx + 1] * sqrt_dt;
        const float dw2 = dW[idx + 2] * sqrt_dt;

        // Y update (uses current-step z, f)
        Y = Y - f * DT + (z[0] * dw0 + z[1] * dw1 + z[2] * dw2);

        // y update: y += (-y + q)*dt + (0.2 + 0.1*tanh(y)) * dw
        const float s0 = 0.2f + 0.1f * tanhf(y0);
        const float s1 = 0.2f + 0.1f * tanhf(y1);
        const float s2 = 0.2f + 0.1f * tanhf(y2);
        y0 = y0 + (qq - y0) * DT + s0 * dw0;
        y1 = y1 + (qq - y1) * DT + s1 * dw1;
        y2 = y2 + (qq - y2) * DT + s2 * dw2;
    }

    const float term = y0 * y0 + y1 * y1 + y2 * y2;
    const float d    = Y - term;
    float val = d * d;

    // wave(64) shuffle reduction
#pragma unroll
    for (int off = 32; off > 0; off >>= 1)
        val += __shfl_down(val, off, 64);

    __shared__ float wsum[4];
    const int lane = threadIdx.x & 63;
    const int wid  = threadIdx.x >> 6;
    if (lane == 0) wsum[wid] = val;
    __syncthreads();
    if (threadIdx.x == 0) {
        float s = wsum[0] + wsum[1] + wsum[2] + wsum[3];
        atomicAdd(out, s * (1.0f / (float)B));
    }
}

extern "C" void kernel_launch(void* const* d_in, const int* in_sizes, int n_in,
                              void* d_out, int out_size, void* d_ws, size_t ws_size,
                              hipStream_t stream) {
    const float* y0  = (const float*)d_in[0];
    const float* Y0  = (const float*)d_in[1];
    const float* qW1 = (const float*)d_in[2];
    const float* qb1 = (const float*)d_in[3];
    const float* qW2 = (const float*)d_in[4];
    const float* qb2 = (const float*)d_in[5];
    const float* qW3 = (const float*)d_in[6];
    const float* qb3 = (const float*)d_in[7];
    const float* zW1 = (const float*)d_in[8];
    const float* zb1 = (const float*)d_in[9];
    const float* zW2 = (const float*)d_in[10];
    const float* zb2 = (const float*)d_in[11];
    const float* zW3 = (const float*)d_in[12];
    const float* zb3 = (const float*)d_in[13];
    const float* dW  = (const float*)d_in[14];

    const int B = in_sizes[14] / (N_STEPS * 3);   // 131072
    float* out = (float*)d_out;

    hipMemsetAsync(out, 0, sizeof(float), stream);

    const int threads = 256;
    const int blocks  = (B + threads - 1) / threads;
    bsde_kernel<<<blocks, threads, 0, stream>>>(
        y0, Y0, qW1, qb1, qW2, qb2, qW3, qb3,
        zW1, zb1, zW2, zb2, zW3, zb3, dW, out, B);
}

// Round 2
// 1471.551 us; speedup vs baseline: 1.2647x; 1.2647x over previous
//
#include <hip/hip_runtime.h>
#include <math.h>

#define N_STEPS 50
#define DT 0.02f

// Two-hidden-layer MLP, input x[4], hidden 64/64, NOUT outputs.
// Weights are wave-uniform -> all weight indices are loop-uniform so the
// compiler emits s_load (SGPR operand to v_fmac), costing no VALU slots.
// Layer1 is fused into the layer2 i-loop so no h1[64] register array with
// a dynamic index exists; acc[64] is only indexed by unrolled constants.
template <int NOUT>
__device__ inline void mlp2(const float* __restrict__ W1, const float* __restrict__ b1,
                            const float* __restrict__ W2, const float* __restrict__ b2,
                            const float* __restrict__ W3, const float* __restrict__ b3,
                            float x0, float x1, float x2, float x3,
                            float* __restrict__ outv)
{
    float acc[64];
#pragma unroll
    for (int j = 0; j < 64; ++j) acc[j] = b2[j];

    for (int i = 0; i < 64; ++i) {            // rolled: small code, uniform s_loads
        float h = b1[i];
        h = fmaf(x0, W1[i],        h);
        h = fmaf(x1, W1[64 + i],   h);
        h = fmaf(x2, W1[128 + i],  h);
        h = fmaf(x3, W1[192 + i],  h);
        h = fmaxf(h, 0.0f);
        const float* __restrict__ w2row = W2 + i * 64;
#pragma unroll
        for (int j = 0; j < 64; ++j) acc[j] = fmaf(h, w2row[j], acc[j]);
    }

#pragma unroll
    for (int c = 0; c < NOUT; ++c) outv[c] = b3[c];
#pragma unroll
    for (int j = 0; j < 64; ++j) {
        float hr = fmaxf(acc[j], 0.0f);
#pragma unroll
        for (int c = 0; c < NOUT; ++c) outv[c] = fmaf(hr, W3[j * NOUT + c], outv[c]);
    }
}

// Block = 256 threads = 4 waves, handles 128 paths.
//   wave 0: z-net for paths [base,     base+64)
//   wave 1: q-net for paths [base,     base+64)
//   wave 2: z-net for paths [base+64,  base+128)
//   wave 3: q-net for paths [base+64,  base+128)
// Net assignment is wave-granular so weight addresses stay wave-uniform
// (s_load). z<->q exchanged via double-buffered LDS, 1 barrier/step. Both
// waves of a pair integrate the identical y-state redundantly (bitwise-same
// f32 sequence), so no state exchange is needed.
__global__ __launch_bounds__(256) void bsde_kernel(
    const float* __restrict__ y0v, const float* __restrict__ Y0v,
    const float* __restrict__ qW1, const float* __restrict__ qb1,
    const float* __restrict__ qW2, const float* __restrict__ qb2,
    const float* __restrict__ qW3, const float* __restrict__ qb3,
    const float* __restrict__ zW1, const float* __restrict__ zb1,
    const float* __restrict__ zW2, const float* __restrict__ zb2,
    const float* __restrict__ zW3, const float* __restrict__ zb3,
    const float* __restrict__ dW,
    float* __restrict__ out, int B)
{
    const int lane = threadIdx.x & 63;
    const int wave = threadIdx.x >> 6;
    const int net  = wave & 1;            // 0 = z-net, 1 = q-net
    const int pair = wave >> 1;           // 0 or 1
    const int lp   = pair * 64 + lane;    // 0..127 within block
    const int p    = blockIdx.x * 128 + lp;

    __shared__ float zbuf[2][128][3];     // stride-3 floats: 2 lanes/bank, free
    __shared__ float qbuf[2][128];

    const float sqrt_dt = sqrtf(DT);

    float y0 = y0v[0], y1 = y0v[1], y2 = y0v[2];
    float Y  = Y0v[0];

    for (int n = 0; n < N_STEPS; ++n) {
        const float t  = (float)n * DT;
        const int   bu = n & 1;

        if (net == 0) {
            float z[3];
            mlp2<3>(zW1, zb1, zW2, zb2, zW3, zb3, t, y0, y1, y2, z);
            zbuf[bu][lp][0] = z[0];
            zbuf[bu][lp][1] = z[1];
            zbuf[bu][lp][2] = z[2];
        } else {
            float q[1];
            mlp2<1>(qW1, qb1, qW2, qb2, qW3, qb3, t, y0, y1, y2, q);
            qbuf[bu][lp] = q[0];
        }
        __syncthreads();

        const float qq = qbuf[bu][lp];
        const float z0 = zbuf[bu][lp][0];
        const float z1 = zbuf[bu][lp][1];
        const float z2 = zbuf[bu][lp][2];
        const float f  = 0.5f * qq * qq;

        const size_t idx = ((size_t)n * (size_t)B + (size_t)p) * 3;
        const float dw0 = dW[idx + 0] * sqrt_dt;
        const float dw1 = dW[idx + 1] * sqrt_dt;
        const float dw2 = dW[idx + 2] * sqrt_dt;

        Y = Y - f * DT + (z0 * dw0 + z1 * dw1 + z2 * dw2);

        const float s0 = 0.2f + 0.1f * tanhf(y0);
        const float s1 = 0.2f + 0.1f * tanhf(y1);
        const float s2 = 0.2f + 0.1f * tanhf(y2);
        y0 = y0 + (qq - y0) * DT + s0 * dw0;
        y1 = y1 + (qq - y1) * DT + s1 * dw1;
        y2 = y2 + (qq - y2) * DT + s2 * dw2;
    }

    // Only the z-waves contribute each path once.
    if (net == 0) {
        const float term = y0 * y0 + y1 * y1 + y2 * y2;
        const float d    = Y - term;
        float val = d * d;
#pragma unroll
        for (int off = 32; off > 0; off >>= 1)
            val += __shfl_down(val, off, 64);
        if (lane == 0)
            atomicAdd(out, val * (1.0f / (float)B));
    }
}

extern "C" void kernel_launch(void* const* d_in, const int* in_sizes, int n_in,
                              void* d_out, int out_size, void* d_ws, size_t ws_size,
                              hipStream_t stream) {
    const float* y0  = (const float*)d_in[0];
    const float* Y0  = (const float*)d_in[1];
    const float* qW1 = (const float*)d_in[2];
    const float* qb1 = (const float*)d_in[3];
    const float* qW2 = (const float*)d_in[4];
    const float* qb2 = (const float*)d_in[5];
    const float* qW3 = (const float*)d_in[6];
    const float* qb3 = (const float*)d_in[7];
    const float* zW1 = (const float*)d_in[8];
    const float* zb1 = (const float*)d_in[9];
    const float* zW2 = (const float*)d_in[10];
    const float* zb2 = (const float*)d_in[11];
    const float* zW3 = (const float*)d_in[12];
    const float* zb3 = (const float*)d_in[13];
    const float* dW  = (const float*)d_in[14];

    const int B = in_sizes[14] / (N_STEPS * 3);   // 131072
    float* out = (float*)d_out;

    hipMemsetAsync(out, 0, sizeof(float), stream);

    const int threads = 256;                       // 4 waves: 2 path-groups x 2 nets
    const int blocks  = B / 128;                   // 1024 blocks
    bsde_kernel<<<blocks, threads, 0, stream>>>(
        y0, Y0, qW1, qb1, qW2, qb2, qW3, qb3,
        zW1, zb1, zW2, zb2, zW3, zb3, dW, out, B);
}